// Round 5
// baseline (105.340 us; speedup 1.0000x reference)
//
#include <hip/hip_runtime.h>
#include <math.h>

#define HORIZON 20
#define DT      0.1f
#define EPS     1e-4f
#define V_MAX   0.22f
#define W_MAX   2.8f

// K(v,w) table: TN x TN nodes over [TLO,THI]^2; one node = 16 B (6 fp16 + pad).
#define TN     512
#define TLO   -6.5f
#define THI    6.5f
#define TH     ((THI - TLO) / (float)(TN - 1))
#define INV_TH ((float)(TN - 1) / (THI - TLO))

typedef _Float16 h8 __attribute__((ext_vector_type(8)));

// jax.nn.softplus(x) == max(x,0) + log1p(exp(-|x|))
__device__ __forceinline__ float softplus_f(float x) {
    return fmaxf(x, 0.0f) + log1pf(expf(-fabsf(x)));
}

// Exact 20-step Riccati at one (v,w) grid node -> 6 fp16 K values (16 B).
__global__ __launch_bounds__(256) void table_kernel(
    const float* __restrict__ q_raw,
    const float* __restrict__ r_raw,
    const float* __restrict__ qf_raw,
    h8* __restrict__ tbl)
{
    const int idx = blockIdx.x * blockDim.x + threadIdx.x;
    if (idx >= TN * TN) return;
    const int iv = idx & (TN - 1);
    const int iw = idx >> 9;                 // TN == 512
    const float vref = TLO + TH * (float)iv;
    const float wref = TLO + TH * (float)iw;

    const float q0  = softplus_f(q_raw[0])  + EPS;
    const float q1  = softplus_f(q_raw[1])  + EPS;
    const float q2  = softplus_f(q_raw[2])  + EPS;
    const float r0e = softplus_f(r_raw[0])  + EPS + EPS;   // R diag + eps*I2
    const float r1e = softplus_f(r_raw[1])  + EPS + EPS;
    const float qf0 = softplus_f(qf_raw[0]) + EPS;
    const float qf1 = softplus_f(qf_raw[1]) + EPS;
    const float qf2 = softplus_f(qf_raw[2]) + EPS;

    const float dt  = DT;
    const float dt2 = dt * dt;
    const float dtw = dt * wref;
    const float dtv = dt * vref;

    float p00 = qf0, p01 = 0.f, p02 = 0.f, p11 = qf1, p12 = 0.f, p22 = qf2;
    float k00 = 0.f, k01 = 0.f, k02 = 0.f, k10 = 0.f, k11 = 0.f, k12 = 0.f;

    // A = [[1,dtw,0],[-dtw,1,dtv],[0,0,1]], B = [[-dt,0],[0,0],[0,-dt]]
    // Rows of (BtP@A)/(-dt) are columns 0,2 of T = A^T P.
    #pragma unroll
    for (int t = 0; t < HORIZON; ++t) {
        const float t00 = p00 - dtw * p01;
        const float t01 = p01 - dtw * p11;
        const float t02 = p02 - dtw * p12;
        const float t10 = dtw * p00 + p01;
        const float t11 = dtw * p01 + p11;
        const float t12 = dtw * p02 + p12;
        const float t20 = dtv * p01 + p02;
        const float t21 = dtv * p11 + p12;
        const float t22 = dtv * p12 + p22;

        const float s00 = r0e + dt2 * p00;
        const float s01 =       dt2 * p02;
        const float s11 = r1e + dt2 * p22;
        const float c = -dt * __builtin_amdgcn_rcpf(s00 * s11 - s01 * s01);
        const float cs11 = c * s11, cs01 = c * s01, cs00 = c * s00;

        k00 = cs11 * t00 - cs01 * t02;
        k01 = cs11 * t10 - cs01 * t12;
        k02 = cs11 * t20 - cs01 * t22;
        k10 = cs00 * t02 - cs01 * t00;
        k11 = cs00 * t12 - cs01 * t10;
        k12 = cs00 * t22 - cs01 * t20;

        const float a00 = 1.0f + dt * k00;
        const float a01 = dtw  + dt * k01;
        const float a02 =        dt * k02;
        const float a20 =        dt * k10;
        const float a21 =        dt * k11;
        const float a22 = 1.0f + dt * k12;

        p00 = q0 + t00 * a00 - t01 * dtw + t02 * a20;
        p01 =      t00 * a01 + t01       + t02 * a21;
        p02 =      t00 * a02 + t01 * dtv + t02 * a22;
        p11 = q1 + t10 * a01 + t11       + t12 * a21;
        p12 =      t10 * a02 + t11 * dtv + t12 * a22;
        p22 = q2 + t20 * a02 + t21 * dtv + t22 * a22;
    }

    h8 pk;
    pk[0] = (_Float16)k00; pk[1] = (_Float16)k01; pk[2] = (_Float16)k02;
    pk[3] = (_Float16)k10; pk[4] = (_Float16)k11; pk[5] = (_Float16)k12;
    pk[6] = (_Float16)0.f; pk[7] = (_Float16)0.f;
    tbl[idx] = pk;
}

// Bilinear K lookup (4 corner loads of 16 B) + output for one element.
__device__ __forceinline__ float2 eval_elem(
    const h8* __restrict__ tbl,
    float e0, float e1, float e2, float vref, float wref)
{
    float fv = (vref - TLO) * INV_TH;
    float fw = (wref - TLO) * INV_TH;
    fv = fminf(fmaxf(fv, 0.0f), (float)(TN - 1) - 1e-3f);
    fw = fminf(fmaxf(fw, 0.0f), (float)(TN - 1) - 1e-3f);
    const int iv = (int)fv;  const float av = fv - (float)iv;
    const int iw = (int)fw;  const float aw = fw - (float)iw;

    const int b = iw * TN + iv;
    const h8 A = tbl[b],      B = tbl[b + 1];       // (iw,   iv) (iw,   iv+1)
    const h8 C = tbl[b + TN], D = tbl[b + TN + 1];  // (iw+1, iv) (iw+1, iv+1)

    const float u00 = (1.0f - av) * (1.0f - aw);
    const float u01 = av * (1.0f - aw);
    const float u10 = (1.0f - av) * aw;
    const float u11 = av * aw;

    const float k0 = u00*(float)A[0] + u01*(float)B[0] + u10*(float)C[0] + u11*(float)D[0];
    const float k1 = u00*(float)A[1] + u01*(float)B[1] + u10*(float)C[1] + u11*(float)D[1];
    const float k2 = u00*(float)A[2] + u01*(float)B[2] + u10*(float)C[2] + u11*(float)D[2];
    const float k3 = u00*(float)A[3] + u01*(float)B[3] + u10*(float)C[3] + u11*(float)D[3];
    const float k4 = u00*(float)A[4] + u01*(float)B[4] + u10*(float)C[4] + u11*(float)D[4];
    const float k5 = u00*(float)A[5] + u01*(float)B[5] + u10*(float)C[5] + u11*(float)D[5];

    // delta_u = -K e; mean = u_ref + delta_u; clip
    const float du0 = k0 * e0 + k1 * e1 + k2 * e2;
    const float du1 = k3 * e0 + k4 * e1 + k5 * e2;
    const float v = fminf(fmaxf(vref - du0, -V_MAX), V_MAX);
    const float w = fminf(fmaxf(wref - du1, -W_MAX), W_MAX);
    return make_float2(v, w);
}

template <bool TAIL>
__global__ __launch_bounds__(256) void lqr_main(
    const float* __restrict__ ref,     // (B,5)
    const h8* __restrict__ tbl,        // K table (d_ws)
    float* __restrict__ out,           // (B,2)
    int batch)
{
    const int i = blockIdx.x * blockDim.x + threadIdx.x;  // pair index
    const int i0 = 2 * i;
    if (i0 >= batch) return;

    if (!TAIL || i0 + 1 < batch) {
        const float2* r2 = reinterpret_cast<const float2*>(ref) + 5 * i;
        const float2 d0 = r2[0], d1 = r2[1], d2 = r2[2], d3 = r2[3], d4 = r2[4];
        // elem0: e=(d0.x,d0.y,d1.x) u=(d1.y,d2.x); elem1: e=(d2.y,d3.x,d3.y) u=(d4.x,d4.y)
        const float2 o0 = eval_elem(tbl, d0.x, d0.y, d1.x, d1.y, d2.x);
        const float2 o1 = eval_elem(tbl, d2.y, d3.x, d3.y, d4.x, d4.y);
        float4* out4 = reinterpret_cast<float4*>(out);
        out4[i] = make_float4(o0.x, o0.y, o1.x, o1.y);
    } else {
        const float* r = ref + 5 * i0;
        const float2 o0 = eval_elem(tbl, r[0], r[1], r[2], r[3], r[4]);
        float2* out2 = reinterpret_cast<float2*>(out);
        out2[i0] = o0;
    }
}

extern "C" void kernel_launch(void* const* d_in, const int* in_sizes, int n_in,
                              void* d_out, int out_size, void* d_ws, size_t ws_size,
                              hipStream_t stream) {
    const float* ref    = (const float*)d_in[0];
    const float* q_raw  = (const float*)d_in[1];
    const float* r_raw  = (const float*)d_in[2];
    const float* qf_raw = (const float*)d_in[3];
    float* out = (float*)d_out;
    h8* tbl = (h8*)d_ws;                       // TN*TN*16 B = 4 MB

    const int batch = in_sizes[0] / 5;
    const int pairs = (batch + 1) / 2;
    const int block = 256;

    table_kernel<<<(TN * TN + block - 1) / block, block, 0, stream>>>(
        q_raw, r_raw, qf_raw, tbl);

    const int grid = (pairs + block - 1) / block;
    if (batch & 1)
        lqr_main<true><<<grid, block, 0, stream>>>(ref, tbl, out, batch);
    else
        lqr_main<false><<<grid, block, 0, stream>>>(ref, tbl, out, batch);
}

// Round 6
// 94.803 us; speedup vs baseline: 1.1112x; 1.1112x over previous
//
#include <hip/hip_runtime.h>
#include <math.h>

#define HORIZON 20
#define DT      0.1f
#define EPS     1e-4f
#define V_MAX   0.22f
#define W_MAX   2.8f

// K(v,w) table with symmetry fold K(-v,-w) = K(v,w)*diag(1,-1,1):
// store w in [0,4], v in [-4,4]. 101x51 nodes, h=0.08.
// 6 fp16 per node as 3 SoA dword arrays -> 3*5151*4 = 61,812 B (fits 64 KB LDS).
#define NV 101
#define NW 51
#define NODES (NV * NW)
#define HSTEP 0.08f
#define INV_H 12.5f

typedef _Float16 h2 __attribute__((ext_vector_type(2)));

__device__ __forceinline__ float softplus_f(float x) {
    return fmaxf(x, 0.0f) + log1pf(expf(-fabsf(x)));
}

__device__ __forceinline__ float2 up2(unsigned u) {
    h2 h = __builtin_bit_cast(h2, u);
    return make_float2((float)h[0], (float)h[1]);
}

// Exact 20-step Riccati at (vref, wref) -> K (2x3) in K[6] row-major.
__device__ __forceinline__ void riccati_K(
    float vref, float wref,
    const float* __restrict__ q_raw, const float* __restrict__ r_raw,
    const float* __restrict__ qf_raw, float K[6])
{
    const float q0  = softplus_f(q_raw[0])  + EPS;
    const float q1  = softplus_f(q_raw[1])  + EPS;
    const float q2  = softplus_f(q_raw[2])  + EPS;
    const float r0e = softplus_f(r_raw[0])  + EPS + EPS;   // R diag + eps*I2
    const float r1e = softplus_f(r_raw[1])  + EPS + EPS;
    const float qf0 = softplus_f(qf_raw[0]) + EPS;
    const float qf1 = softplus_f(qf_raw[1]) + EPS;
    const float qf2 = softplus_f(qf_raw[2]) + EPS;

    const float dt  = DT;
    const float dt2 = dt * dt;
    const float dtw = dt * wref;
    const float dtv = dt * vref;

    float p00 = qf0, p01 = 0.f, p02 = 0.f, p11 = qf1, p12 = 0.f, p22 = qf2;
    float k00 = 0.f, k01 = 0.f, k02 = 0.f, k10 = 0.f, k11 = 0.f, k12 = 0.f;

    // A = [[1,dtw,0],[-dtw,1,dtv],[0,0,1]], B = [[-dt,0],[0,0],[0,-dt]]
    // Rows of (BtP@A)/(-dt) are columns 0,2 of T = A^T P.
    #pragma unroll
    for (int t = 0; t < HORIZON; ++t) {
        const float t00 = p00 - dtw * p01;
        const float t01 = p01 - dtw * p11;
        const float t02 = p02 - dtw * p12;
        const float t10 = dtw * p00 + p01;
        const float t11 = dtw * p01 + p11;
        const float t12 = dtw * p02 + p12;
        const float t20 = dtv * p01 + p02;
        const float t21 = dtv * p11 + p12;
        const float t22 = dtv * p12 + p22;

        const float s00 = r0e + dt2 * p00;
        const float s01 =       dt2 * p02;
        const float s11 = r1e + dt2 * p22;
        const float c = -dt * __builtin_amdgcn_rcpf(s00 * s11 - s01 * s01);
        const float cs11 = c * s11, cs01 = c * s01, cs00 = c * s00;

        k00 = cs11 * t00 - cs01 * t02;
        k01 = cs11 * t10 - cs01 * t12;
        k02 = cs11 * t20 - cs01 * t22;
        k10 = cs00 * t02 - cs01 * t00;
        k11 = cs00 * t12 - cs01 * t10;
        k12 = cs00 * t22 - cs01 * t20;

        const float a00 = 1.0f + dt * k00;
        const float a01 = dtw  + dt * k01;
        const float a02 =        dt * k02;
        const float a20 =        dt * k10;
        const float a21 =        dt * k11;
        const float a22 = 1.0f + dt * k12;

        p00 = q0 + t00 * a00 - t01 * dtw + t02 * a20;
        p01 =      t00 * a01 + t01       + t02 * a21;
        p02 =      t00 * a02 + t01 * dtv + t02 * a22;
        p11 = q1 + t10 * a01 + t11       + t12 * a21;
        p12 =      t10 * a02 + t11 * dtv + t12 * a22;
        p22 = q2 + t20 * a02 + t21 * dtv + t22 * a22;
    }
    K[0] = k00; K[1] = k01; K[2] = k02;
    K[3] = k10; K[4] = k11; K[5] = k12;
}

// Build global SoA table: a0=(k00,k01) a1=(k02,k10) a2=(k11,k12), fp16 pairs.
__global__ __launch_bounds__(256) void table_kernel(
    const float* __restrict__ q_raw, const float* __restrict__ r_raw,
    const float* __restrict__ qf_raw, unsigned* __restrict__ tbl)
{
    const int idx = blockIdx.x * blockDim.x + threadIdx.x;
    if (idx >= NODES) return;
    const int iv = idx % NV;
    const int iw = idx / NV;
    const float v = fmaf(HSTEP, (float)iv, -4.0f);
    const float w = HSTEP * (float)iw;
    float K[6];
    riccati_K(v, w, q_raw, r_raw, qf_raw, K);
    h2 p0, p1, p2;
    p0[0] = (_Float16)K[0]; p0[1] = (_Float16)K[1];
    p1[0] = (_Float16)K[2]; p1[1] = (_Float16)K[3];
    p2[0] = (_Float16)K[4]; p2[1] = (_Float16)K[5];
    tbl[idx]             = __builtin_bit_cast(unsigned, p0);
    tbl[NODES + idx]     = __builtin_bit_cast(unsigned, p1);
    tbl[2 * NODES + idx] = __builtin_bit_cast(unsigned, p2);
}

// One element: fold symmetry, bilinear from LDS (12 ds_read_b32), rare exact fallback.
__device__ __forceinline__ float2 eval_one(
    const unsigned* __restrict__ a0, const unsigned* __restrict__ a1,
    const unsigned* __restrict__ a2,
    const float* __restrict__ q_raw, const float* __restrict__ r_raw,
    const float* __restrict__ qf_raw,
    float e0, float e1, float e2, float vref, float wref)
{
    const float s  = (wref < 0.0f) ? -1.0f : 1.0f;   // fold: (v,w,e1) -> s*(v,w,e1)
    const float vf = s * vref, wf = s * wref, e1f = s * e1;

    float k0, k1, k2, k3, k4, k5;
    if (fabsf(vf) <= 4.0f && wf <= 4.0f) {
        float fv = (vf + 4.0f) * INV_H;              // [0,100]
        float fw = wf * INV_H;                       // [0,50]
        int iv = (int)fv; iv = iv > NV - 2 ? NV - 2 : iv;
        int iw = (int)fw; iw = iw > NW - 2 ? NW - 2 : iw;
        const float av = fv - (float)iv;
        const float aw = fw - (float)iw;
        const int b = iw * NV + iv;

        const float u00 = (1.0f - av) * (1.0f - aw);
        const float u01 = av * (1.0f - aw);
        const float u10 = (1.0f - av) * aw;
        const float u11 = av * aw;

        const float2 A0 = up2(a0[b]), B0 = up2(a0[b + 1]),
                     C0 = up2(a0[b + NV]), D0 = up2(a0[b + NV + 1]);
        const float2 A1 = up2(a1[b]), B1 = up2(a1[b + 1]),
                     C1 = up2(a1[b + NV]), D1 = up2(a1[b + NV + 1]);
        const float2 A2 = up2(a2[b]), B2 = up2(a2[b + 1]),
                     C2 = up2(a2[b + NV]), D2 = up2(a2[b + NV + 1]);

        k0 = u00 * A0.x + u01 * B0.x + u10 * C0.x + u11 * D0.x;
        k1 = u00 * A0.y + u01 * B0.y + u10 * C0.y + u11 * D0.y;
        k2 = u00 * A1.x + u01 * B1.x + u10 * C1.x + u11 * D1.x;
        k3 = u00 * A1.y + u01 * B1.y + u10 * C1.y + u11 * D1.y;
        k4 = u00 * A2.x + u01 * B2.x + u10 * C2.x + u11 * D2.x;
        k5 = u00 * A2.y + u01 * B2.y + u10 * C2.y + u11 * D2.y;
    } else {
        // exact fallback at the folded point (identity K(vf,wf) with e1f is exact)
        float K[6];
        riccati_K(vf, wf, q_raw, r_raw, qf_raw, K);
        k0 = K[0]; k1 = K[1]; k2 = K[2]; k3 = K[3]; k4 = K[4]; k5 = K[5];
    }

    const float du0 = k0 * e0 + k1 * e1f + k2 * e2;
    const float du1 = k3 * e0 + k4 * e1f + k5 * e2;
    const float v = fminf(fmaxf(vref - du0, -V_MAX), V_MAX);
    const float w = fminf(fmaxf(wref - du1, -W_MAX), W_MAX);
    return make_float2(v, w);
}

template <bool TAIL>
__global__ __launch_bounds__(1024) void lqr_main(
    const float* __restrict__ ref,     // (B,5)
    const unsigned* __restrict__ tbl,  // global SoA table (d_ws)
    const float* __restrict__ q_raw, const float* __restrict__ r_raw,
    const float* __restrict__ qf_raw,
    float* __restrict__ out,           // (B,2)
    int batch)
{
    __shared__ unsigned lds[3 * NODES];            // 61,812 B
    for (int j = threadIdx.x; j < 3 * NODES; j += 1024)
        lds[j] = tbl[j];
    __syncthreads();
    const unsigned* a0 = lds;
    const unsigned* a1 = lds + NODES;
    const unsigned* a2 = lds + 2 * NODES;

    const int i = blockIdx.x * 1024 + threadIdx.x;   // pair index
    const int i0 = 2 * i;
    if (i0 >= batch) return;

    if (!TAIL || i0 + 1 < batch) {
        const float2* r2 = reinterpret_cast<const float2*>(ref) + 5 * i;
        const float2 d0 = r2[0], d1 = r2[1], d2 = r2[2], d3 = r2[3], d4 = r2[4];
        // elem0: e=(d0.x,d0.y,d1.x) u=(d1.y,d2.x); elem1: e=(d2.y,d3.x,d3.y) u=(d4.x,d4.y)
        const float2 o0 = eval_one(a0, a1, a2, q_raw, r_raw, qf_raw,
                                   d0.x, d0.y, d1.x, d1.y, d2.x);
        const float2 o1 = eval_one(a0, a1, a2, q_raw, r_raw, qf_raw,
                                   d2.y, d3.x, d3.y, d4.x, d4.y);
        float4* out4 = reinterpret_cast<float4*>(out);
        out4[i] = make_float4(o0.x, o0.y, o1.x, o1.y);
    } else {
        const float* r = ref + 5 * i0;
        const float2 o0 = eval_one(a0, a1, a2, q_raw, r_raw, qf_raw,
                                   r[0], r[1], r[2], r[3], r[4]);
        float2* out2 = reinterpret_cast<float2*>(out);
        out2[i0] = o0;
    }
}

extern "C" void kernel_launch(void* const* d_in, const int* in_sizes, int n_in,
                              void* d_out, int out_size, void* d_ws, size_t ws_size,
                              hipStream_t stream) {
    const float* ref    = (const float*)d_in[0];
    const float* q_raw  = (const float*)d_in[1];
    const float* r_raw  = (const float*)d_in[2];
    const float* qf_raw = (const float*)d_in[3];
    float* out = (float*)d_out;
    unsigned* tbl = (unsigned*)d_ws;               // 3*NODES dwords ~= 62 KB

    const int batch = in_sizes[0] / 5;
    const int pairs = (batch + 1) / 2;

    table_kernel<<<(NODES + 255) / 256, 256, 0, stream>>>(q_raw, r_raw, qf_raw, tbl);

    const int grid = (pairs + 1023) / 1024;
    if (batch & 1)
        lqr_main<true><<<grid, 1024, 0, stream>>>(ref, tbl, q_raw, r_raw, qf_raw, out, batch);
    else
        lqr_main<false><<<grid, 1024, 0, stream>>>(ref, tbl, q_raw, r_raw, qf_raw, out, batch);
}

// Round 7
// 90.552 us; speedup vs baseline: 1.1633x; 1.0469x over previous
//
#include <hip/hip_runtime.h>
#include <math.h>

#define HORIZON 20
#define DT      0.1f
#define EPS     1e-4f
#define V_MAX   0.22f
#define W_MAX   2.8f

// K(v,w) table with symmetry fold K(-v,-w) = K(v,w)*diag(1,-1,1):
// store w in [0,4], v in [-4,4]. 101x51 nodes, h=0.08.
// 6 fp16 per node as 3 SoA dword arrays -> 3*5151*4 = 61,812 B (fits 64 KB LDS).
#define NV 101
#define NW 51
#define NODES (NV * NW)
#define HSTEP 0.08f
#define INV_H 12.5f

// d_ws layout (bytes): [0,4) oor-count; [256, 256+4*CAP) oor index list;
// [1 MiB, ...) the 62 KB K-table.
#define CAP        65536
#define LIST_OFF   64          // dwords
#define TBL_OFF    262144      // dwords (1 MiB)

typedef _Float16 h2 __attribute__((ext_vector_type(2)));

__device__ __forceinline__ float softplus_f(float x) {
    return fmaxf(x, 0.0f) + log1pf(expf(-fabsf(x)));
}

__device__ __forceinline__ float2 up2(unsigned u) {
    h2 h = __builtin_bit_cast(h2, u);
    return make_float2((float)h[0], (float)h[1]);
}

// Exact 20-step Riccati at (vref, wref) -> K (2x3) in K[6] row-major.
__device__ void riccati_K(
    float vref, float wref,
    const float* __restrict__ q_raw, const float* __restrict__ r_raw,
    const float* __restrict__ qf_raw, float K[6])
{
    const float q0  = softplus_f(q_raw[0])  + EPS;
    const float q1  = softplus_f(q_raw[1])  + EPS;
    const float q2  = softplus_f(q_raw[2])  + EPS;
    const float r0e = softplus_f(r_raw[0])  + EPS + EPS;   // R diag + eps*I2
    const float r1e = softplus_f(r_raw[1])  + EPS + EPS;
    const float qf0 = softplus_f(qf_raw[0]) + EPS;
    const float qf1 = softplus_f(qf_raw[1]) + EPS;
    const float qf2 = softplus_f(qf_raw[2]) + EPS;

    const float dt  = DT;
    const float dt2 = dt * dt;
    const float dtw = dt * wref;
    const float dtv = dt * vref;

    float p00 = qf0, p01 = 0.f, p02 = 0.f, p11 = qf1, p12 = 0.f, p22 = qf2;
    float k00 = 0.f, k01 = 0.f, k02 = 0.f, k10 = 0.f, k11 = 0.f, k12 = 0.f;

    // A = [[1,dtw,0],[-dtw,1,dtv],[0,0,1]], B = [[-dt,0],[0,0],[0,-dt]]
    // Rows of (BtP@A)/(-dt) are columns 0,2 of T = A^T P.
    #pragma unroll
    for (int t = 0; t < HORIZON; ++t) {
        const float t00 = p00 - dtw * p01;
        const float t01 = p01 - dtw * p11;
        const float t02 = p02 - dtw * p12;
        const float t10 = dtw * p00 + p01;
        const float t11 = dtw * p01 + p11;
        const float t12 = dtw * p02 + p12;
        const float t20 = dtv * p01 + p02;
        const float t21 = dtv * p11 + p12;
        const float t22 = dtv * p12 + p22;

        const float s00 = r0e + dt2 * p00;
        const float s01 =       dt2 * p02;
        const float s11 = r1e + dt2 * p22;
        const float c = -dt * __builtin_amdgcn_rcpf(s00 * s11 - s01 * s01);
        const float cs11 = c * s11, cs01 = c * s01, cs00 = c * s00;

        k00 = cs11 * t00 - cs01 * t02;
        k01 = cs11 * t10 - cs01 * t12;
        k02 = cs11 * t20 - cs01 * t22;
        k10 = cs00 * t02 - cs01 * t00;
        k11 = cs00 * t12 - cs01 * t10;
        k12 = cs00 * t22 - cs01 * t20;

        const float a00 = 1.0f + dt * k00;
        const float a01 = dtw  + dt * k01;
        const float a02 =        dt * k02;
        const float a20 =        dt * k10;
        const float a21 =        dt * k11;
        const float a22 = 1.0f + dt * k12;

        p00 = q0 + t00 * a00 - t01 * dtw + t02 * a20;
        p01 =      t00 * a01 + t01       + t02 * a21;
        p02 =      t00 * a02 + t01 * dtv + t02 * a22;
        p11 = q1 + t10 * a01 + t11       + t12 * a21;
        p12 =      t10 * a02 + t11 * dtv + t12 * a22;
        p22 = q2 + t20 * a02 + t21 * dtv + t22 * a22;
    }
    K[0] = k00; K[1] = k01; K[2] = k02;
    K[3] = k10; K[4] = k11; K[5] = k12;
}

// Build table (SoA fp16 pairs) + zero the oor counter.
__global__ __launch_bounds__(256) void table_kernel(
    const float* __restrict__ q_raw, const float* __restrict__ r_raw,
    const float* __restrict__ qf_raw, unsigned* __restrict__ ws)
{
    const int idx = blockIdx.x * blockDim.x + threadIdx.x;
    if (idx == 0) ws[0] = 0u;                      // oor count
    if (idx >= NODES) return;
    const int iv = idx % NV;
    const int iw = idx / NV;
    const float v = fmaf(HSTEP, (float)iv, -4.0f);
    const float w = HSTEP * (float)iw;
    float K[6];
    riccati_K(v, w, q_raw, r_raw, qf_raw, K);
    h2 p0, p1, p2;
    p0[0] = (_Float16)K[0]; p0[1] = (_Float16)K[1];
    p1[0] = (_Float16)K[2]; p1[1] = (_Float16)K[3];
    p2[0] = (_Float16)K[4]; p2[1] = (_Float16)K[5];
    unsigned* tbl = ws + TBL_OFF;
    tbl[idx]             = __builtin_bit_cast(unsigned, p0);
    tbl[NODES + idx]     = __builtin_bit_cast(unsigned, p1);
    tbl[2 * NODES + idx] = __builtin_bit_cast(unsigned, p2);
}

// Clamped bilinear gather from LDS. Sets *oor if the true point is outside.
__device__ __forceinline__ float2 eval_one(
    const unsigned* __restrict__ a0, const unsigned* __restrict__ a1,
    const unsigned* __restrict__ a2,
    float e0, float e1, float e2, float vref, float wref, bool* oor)
{
    const float s  = (wref < 0.0f) ? -1.0f : 1.0f;   // fold: (v,w,e1) -> s*(v,w,e1)
    const float vf = s * vref, wf = s * wref, e1f = s * e1;

    *oor = (vf < -4.0f) | (vf > 4.0f) | (wf > 4.0f);

    float fv = (vf + 4.0f) * INV_H;
    float fw = wf * INV_H;
    fv = fminf(fmaxf(fv, 0.0f), (float)(NV - 1) - 1e-3f);
    fw = fminf(fmaxf(fw, 0.0f), (float)(NW - 1) - 1e-3f);
    const int iv = (int)fv;  const float av = fv - (float)iv;
    const int iw = (int)fw;  const float aw = fw - (float)iw;
    const int b = iw * NV + iv;

    const float u00 = (1.0f - av) * (1.0f - aw);
    const float u01 = av * (1.0f - aw);
    const float u10 = (1.0f - av) * aw;
    const float u11 = av * aw;

    const float2 A0 = up2(a0[b]), B0 = up2(a0[b + 1]),
                 C0 = up2(a0[b + NV]), D0 = up2(a0[b + NV + 1]);
    const float2 A1 = up2(a1[b]), B1 = up2(a1[b + 1]),
                 C1 = up2(a1[b + NV]), D1 = up2(a1[b + NV + 1]);
    const float2 A2 = up2(a2[b]), B2 = up2(a2[b + 1]),
                 C2 = up2(a2[b + NV]), D2 = up2(a2[b + NV + 1]);

    const float k0 = u00 * A0.x + u01 * B0.x + u10 * C0.x + u11 * D0.x;
    const float k1 = u00 * A0.y + u01 * B0.y + u10 * C0.y + u11 * D0.y;
    const float k2 = u00 * A1.x + u01 * B1.x + u10 * C1.x + u11 * D1.x;
    const float k3 = u00 * A1.y + u01 * B1.y + u10 * C1.y + u11 * D1.y;
    const float k4 = u00 * A2.x + u01 * B2.x + u10 * C2.x + u11 * D2.x;
    const float k5 = u00 * A2.y + u01 * B2.y + u10 * C2.y + u11 * D2.y;

    const float du0 = k0 * e0 + k1 * e1f + k2 * e2;
    const float du1 = k3 * e0 + k4 * e1f + k5 * e2;
    const float v = fminf(fmaxf(vref - du0, -V_MAX), V_MAX);
    const float w = fminf(fmaxf(wref - du1, -W_MAX), W_MAX);
    return make_float2(v, w);
}

// 4 elements per thread; float4 loads (80*tid is 16B-aligned). No fallback here.
__global__ __launch_bounds__(512, 4) void lqr_main(
    const float* __restrict__ ref,      // (B,5)
    unsigned* __restrict__ ws,          // count / list / table
    float* __restrict__ out,            // (B,2)
    int batch)
{
    __shared__ unsigned lds[3 * NODES];             // 61,812 B
    const unsigned* tbl = ws + TBL_OFF;
    for (int j = threadIdx.x; j < 3 * NODES; j += 512)
        lds[j] = tbl[j];
    __syncthreads();
    const unsigned* a0 = lds;
    const unsigned* a1 = lds + NODES;
    const unsigned* a2 = lds + 2 * NODES;

    const int t    = blockIdx.x * 512 + threadIdx.x;
    const int base = 4 * t;                         // first element index
    if (base >= batch) return;

    unsigned* cnt  = ws;
    unsigned* list = ws + LIST_OFF;

    if (base + 3 < batch) {
        const float4* r4 = reinterpret_cast<const float4*>(ref + 5 * base);
        const float4 d0 = r4[0], d1 = r4[1], d2 = r4[2], d3 = r4[3], d4 = r4[4];
        const float r[20] = {d0.x,d0.y,d0.z,d0.w, d1.x,d1.y,d1.z,d1.w,
                             d2.x,d2.y,d2.z,d2.w, d3.x,d3.y,d3.z,d3.w,
                             d4.x,d4.y,d4.z,d4.w};
        bool o0, o1, o2, o3;
        const float2 c0 = eval_one(a0,a1,a2, r[0], r[1], r[2], r[3], r[4], &o0);
        const float2 c1 = eval_one(a0,a1,a2, r[5], r[6], r[7], r[8], r[9], &o1);
        const float2 c2 = eval_one(a0,a1,a2, r[10],r[11],r[12],r[13],r[14], &o2);
        const float2 c3 = eval_one(a0,a1,a2, r[15],r[16],r[17],r[18],r[19], &o3);

        float4* o4 = reinterpret_cast<float4*>(out + 2 * base);
        o4[0] = make_float4(c0.x, c0.y, c1.x, c1.y);
        o4[1] = make_float4(c2.x, c2.y, c3.x, c3.y);

        if (o0) { unsigned p = atomicAdd(cnt, 1u); if (p < CAP) list[p] = base;     }
        if (o1) { unsigned p = atomicAdd(cnt, 1u); if (p < CAP) list[p] = base + 1; }
        if (o2) { unsigned p = atomicAdd(cnt, 1u); if (p < CAP) list[p] = base + 2; }
        if (o3) { unsigned p = atomicAdd(cnt, 1u); if (p < CAP) list[p] = base + 3; }
    } else {
        for (int k = 0; k < 4 && base + k < batch; ++k) {
            const float* r = ref + 5 * (base + k);
            bool oo;
            const float2 c = eval_one(a0,a1,a2, r[0], r[1], r[2], r[3], r[4], &oo);
            out[2 * (base + k)]     = c.x;
            out[2 * (base + k) + 1] = c.y;
            if (oo) { unsigned p = atomicAdd(cnt, 1u); if (p < CAP) list[p] = base + k; }
        }
    }
}

// Exact Riccati for the rare out-of-range elements (expected ~hundreds).
__global__ __launch_bounds__(256) void fixup_kernel(
    const float* __restrict__ ref,
    const unsigned* __restrict__ ws,
    const float* __restrict__ q_raw, const float* __restrict__ r_raw,
    const float* __restrict__ qf_raw,
    float* __restrict__ out)
{
    const unsigned n = min(ws[0], (unsigned)CAP);
    const unsigned* list = ws + LIST_OFF;
    for (unsigned j = threadIdx.x; j < n; j += 256) {
        const unsigned idx = list[j];
        const float e0 = ref[5*idx], e1 = ref[5*idx+1], e2 = ref[5*idx+2];
        const float vr = ref[5*idx+3], wr = ref[5*idx+4];
        float K[6];
        riccati_K(vr, wr, q_raw, r_raw, qf_raw, K);
        const float du0 = K[0]*e0 + K[1]*e1 + K[2]*e2;
        const float du1 = K[3]*e0 + K[4]*e1 + K[5]*e2;
        out[2*idx]   = fminf(fmaxf(vr - du0, -V_MAX), V_MAX);
        out[2*idx+1] = fminf(fmaxf(wr - du1, -W_MAX), W_MAX);
    }
}

extern "C" void kernel_launch(void* const* d_in, const int* in_sizes, int n_in,
                              void* d_out, int out_size, void* d_ws, size_t ws_size,
                              hipStream_t stream) {
    const float* ref    = (const float*)d_in[0];
    const float* q_raw  = (const float*)d_in[1];
    const float* r_raw  = (const float*)d_in[2];
    const float* qf_raw = (const float*)d_in[3];
    float* out = (float*)d_out;
    unsigned* ws = (unsigned*)d_ws;

    const int batch = in_sizes[0] / 5;
    const int quads = (batch + 3) / 4;

    table_kernel<<<(NODES + 255) / 256, 256, 0, stream>>>(q_raw, r_raw, qf_raw, ws);

    const int grid = (quads + 511) / 512;
    lqr_main<<<grid, 512, 0, stream>>>(ref, ws, out, batch);

    fixup_kernel<<<1, 256, 0, stream>>>(ref, ws, q_raw, r_raw, qf_raw, out);
}

// Round 8
// 89.231 us; speedup vs baseline: 1.1805x; 1.0148x over previous
//
#include <hip/hip_runtime.h>
#include <math.h>

#define HORIZON 20
#define DT      0.1f
#define EPS     1e-4f
#define V_MAX   0.22f
#define W_MAX   2.8f

// K(v,w) quadrant table. Two exact symmetries:
//  fold1 (verified R5-R7): K(-v,-w) acts as K(v,w) with e1 -> -e1
//  fold2 (T=diag(1,1,-1), U=diag(1,-1)): K(-v,w) = U K(v,w) T
//    => when v1<0: flip e2 and negate du1.
// Table: v,w in [0,4], NQ x NQ nodes, AoS 16 B/node (6 fp16 + pad).
#define NQ     57
#define NODES  (NQ * NQ)
#define QHI    4.0f
#define INV_H  ((float)(NQ - 1) / QHI)     // 14.0

// d_ws layout (dwords): [0] oor count; [64, 64+CAP) oor index list;
// [262144, ...) table (NODES uint4).
#define CAP      65536
#define LIST_OFF 64
#define TBL_OFF  262144

typedef _Float16 h2 __attribute__((ext_vector_type(2)));

__device__ __forceinline__ float softplus_f(float x) {
    return fmaxf(x, 0.0f) + log1pf(expf(-fabsf(x)));
}

// Exact 20-step Riccati at (vref, wref) -> K (2x3) row-major.
__device__ void riccati_K(
    float vref, float wref,
    const float* __restrict__ q_raw, const float* __restrict__ r_raw,
    const float* __restrict__ qf_raw, float K[6])
{
    const float q0  = softplus_f(q_raw[0])  + EPS;
    const float q1  = softplus_f(q_raw[1])  + EPS;
    const float q2  = softplus_f(q_raw[2])  + EPS;
    const float r0e = softplus_f(r_raw[0])  + EPS + EPS;   // R diag + eps*I2
    const float r1e = softplus_f(r_raw[1])  + EPS + EPS;
    const float qf0 = softplus_f(qf_raw[0]) + EPS;
    const float qf1 = softplus_f(qf_raw[1]) + EPS;
    const float qf2 = softplus_f(qf_raw[2]) + EPS;

    const float dt  = DT;
    const float dt2 = dt * dt;
    const float dtw = dt * wref;
    const float dtv = dt * vref;

    float p00 = qf0, p01 = 0.f, p02 = 0.f, p11 = qf1, p12 = 0.f, p22 = qf2;
    float k00 = 0.f, k01 = 0.f, k02 = 0.f, k10 = 0.f, k11 = 0.f, k12 = 0.f;

    #pragma unroll
    for (int t = 0; t < HORIZON; ++t) {
        const float t00 = p00 - dtw * p01;
        const float t01 = p01 - dtw * p11;
        const float t02 = p02 - dtw * p12;
        const float t10 = dtw * p00 + p01;
        const float t11 = dtw * p01 + p11;
        const float t12 = dtw * p02 + p12;
        const float t20 = dtv * p01 + p02;
        const float t21 = dtv * p11 + p12;
        const float t22 = dtv * p12 + p22;

        const float s00 = r0e + dt2 * p00;
        const float s01 =       dt2 * p02;
        const float s11 = r1e + dt2 * p22;
        const float c = -dt * __builtin_amdgcn_rcpf(s00 * s11 - s01 * s01);
        const float cs11 = c * s11, cs01 = c * s01, cs00 = c * s00;

        k00 = cs11 * t00 - cs01 * t02;
        k01 = cs11 * t10 - cs01 * t12;
        k02 = cs11 * t20 - cs01 * t22;
        k10 = cs00 * t02 - cs01 * t00;
        k11 = cs00 * t12 - cs01 * t10;
        k12 = cs00 * t22 - cs01 * t20;

        const float a00 = 1.0f + dt * k00;
        const float a01 = dtw  + dt * k01;
        const float a02 =        dt * k02;
        const float a20 =        dt * k10;
        const float a21 =        dt * k11;
        const float a22 = 1.0f + dt * k12;

        p00 = q0 + t00 * a00 - t01 * dtw + t02 * a20;
        p01 =      t00 * a01 + t01       + t02 * a21;
        p02 =      t00 * a02 + t01 * dtv + t02 * a22;
        p11 = q1 + t10 * a01 + t11       + t12 * a21;
        p12 =      t10 * a02 + t11 * dtv + t12 * a22;
        p22 = q2 + t20 * a02 + t21 * dtv + t22 * a22;
    }
    K[0] = k00; K[1] = k01; K[2] = k02;
    K[3] = k10; K[4] = k11; K[5] = k12;
}

__device__ __forceinline__ unsigned pack2(float a, float b) {
    h2 h; h[0] = (_Float16)a; h[1] = (_Float16)b;
    return __builtin_bit_cast(unsigned, h);
}

// Build quadrant table (AoS uint4 nodes) + zero the oor counter.
__global__ __launch_bounds__(256) void table_kernel(
    const float* __restrict__ q_raw, const float* __restrict__ r_raw,
    const float* __restrict__ qf_raw, unsigned* __restrict__ ws)
{
    const int idx = blockIdx.x * blockDim.x + threadIdx.x;
    if (idx == 0) ws[0] = 0u;
    if (idx >= NODES) return;
    const int iv = idx % NQ;
    const int iw = idx / NQ;
    const float v = (QHI / (float)(NQ - 1)) * (float)iv;
    const float w = (QHI / (float)(NQ - 1)) * (float)iw;
    float K[6];
    riccati_K(v, w, q_raw, r_raw, qf_raw, K);
    uint4* tbl = reinterpret_cast<uint4*>(ws + TBL_OFF);
    tbl[idx] = make_uint4(pack2(K[0], K[1]), pack2(K[2], K[3]),
                          pack2(K[4], K[5]), 0u);
}

// Double-folded bilinear gather: 4x ds_read_b128 + pk_fma_f16 interp.
__device__ __forceinline__ float2 eval_one(
    const uint4* __restrict__ nodes,
    float e0, float e1, float e2, float vref, float wref, bool* oor)
{
    const float s1 = (wref < 0.0f) ? -1.0f : 1.0f;   // fold1: (v,w,e1) -> s1*(v,w,e1)
    const float v1 = s1 * vref, w1 = s1 * wref;
    const float e1f = s1 * e1;
    const float s2 = (v1 < 0.0f) ? -1.0f : 1.0f;     // fold2: flip e2, negate du1
    const float vq = s2 * v1;
    const float e2f = s2 * e2;

    *oor = (vq > QHI) | (w1 > QHI);

    float fv = fminf(vq * INV_H, (float)(NQ - 1) - 1e-3f);
    float fw = fminf(w1 * INV_H, (float)(NQ - 1) - 1e-3f);
    const int iv = (int)fv;  const float av = fv - (float)iv;
    const int iw = (int)fw;  const float aw = fw - (float)iw;
    const int b = iw * NQ + iv;

    const uint4 A = nodes[b],      B = nodes[b + 1];
    const uint4 C = nodes[b + NQ], D = nodes[b + NQ + 1];

    const _Float16 hu00 = (_Float16)((1.0f - av) * (1.0f - aw));
    const _Float16 hu01 = (_Float16)(av * (1.0f - aw));
    const _Float16 hu10 = (_Float16)((1.0f - av) * aw);
    const _Float16 hu11 = (_Float16)(av * aw);
    const h2 W00 = {hu00, hu00}, W01 = {hu01, hu01},
             W10 = {hu10, hu10}, W11 = {hu11, hu11};

    #define H2(u) __builtin_bit_cast(h2, u)
    h2 r0 = W00 * H2(A.x) + W01 * H2(B.x) + W10 * H2(C.x) + W11 * H2(D.x);
    h2 r1 = W00 * H2(A.y) + W01 * H2(B.y) + W10 * H2(C.y) + W11 * H2(D.y);
    h2 r2 = W00 * H2(A.z) + W01 * H2(B.z) + W10 * H2(C.z) + W11 * H2(D.z);
    #undef H2

    const float k0 = (float)r0[0], k1 = (float)r0[1];
    const float k2 = (float)r1[0], k3 = (float)r1[1];
    const float k4 = (float)r2[0], k5 = (float)r2[1];

    const float du0 =       k0 * e0 + k1 * e1f + k2 * e2f;
    const float du1 = s2 * (k3 * e0 + k4 * e1f + k5 * e2f);
    const float v = fminf(fmaxf(vref - du0, -V_MAX), V_MAX);
    const float w = fminf(fmaxf(wref - du1, -W_MAX), W_MAX);
    return make_float2(v, w);
}

// 4 elements/thread; float4 ref loads; no heavy fallback inline.
__global__ __launch_bounds__(512, 4) void lqr_main(
    const float* __restrict__ ref,      // (B,5)
    unsigned* __restrict__ ws,
    float* __restrict__ out,            // (B,2)
    int batch)
{
    __shared__ uint4 lds[NODES];                     // 51,984 B -> 3 blocks/CU
    const uint4* gt = reinterpret_cast<const uint4*>(ws + TBL_OFF);
    for (int j = threadIdx.x; j < NODES; j += 512)
        lds[j] = gt[j];
    __syncthreads();

    const int t    = blockIdx.x * 512 + threadIdx.x;
    const int base = 4 * t;
    if (base >= batch) return;

    unsigned* cnt  = ws;
    unsigned* list = ws + LIST_OFF;

    if (base + 3 < batch) {
        const float4* r4 = reinterpret_cast<const float4*>(ref + 5 * base);
        const float4 d0 = r4[0], d1 = r4[1], d2 = r4[2], d3 = r4[3], d4 = r4[4];
        const float r[20] = {d0.x,d0.y,d0.z,d0.w, d1.x,d1.y,d1.z,d1.w,
                             d2.x,d2.y,d2.z,d2.w, d3.x,d3.y,d3.z,d3.w,
                             d4.x,d4.y,d4.z,d4.w};
        bool o0, o1, o2, o3;
        const float2 c0 = eval_one(lds, r[0], r[1], r[2], r[3], r[4], &o0);
        const float2 c1 = eval_one(lds, r[5], r[6], r[7], r[8], r[9], &o1);
        const float2 c2 = eval_one(lds, r[10],r[11],r[12],r[13],r[14], &o2);
        const float2 c3 = eval_one(lds, r[15],r[16],r[17],r[18],r[19], &o3);

        float4* o4 = reinterpret_cast<float4*>(out + 2 * base);
        o4[0] = make_float4(c0.x, c0.y, c1.x, c1.y);
        o4[1] = make_float4(c2.x, c2.y, c3.x, c3.y);

        if (o0) { unsigned p = atomicAdd(cnt, 1u); if (p < CAP) list[p] = base;     }
        if (o1) { unsigned p = atomicAdd(cnt, 1u); if (p < CAP) list[p] = base + 1; }
        if (o2) { unsigned p = atomicAdd(cnt, 1u); if (p < CAP) list[p] = base + 2; }
        if (o3) { unsigned p = atomicAdd(cnt, 1u); if (p < CAP) list[p] = base + 3; }
    } else {
        for (int k = 0; k < 4 && base + k < batch; ++k) {
            const float* r = ref + 5 * (base + k);
            bool oo;
            const float2 c = eval_one(lds, r[0], r[1], r[2], r[3], r[4], &oo);
            out[2 * (base + k)]     = c.x;
            out[2 * (base + k) + 1] = c.y;
            if (oo) { unsigned p = atomicAdd(cnt, 1u); if (p < CAP) list[p] = base + k; }
        }
    }
}

// Exact Riccati for rare out-of-quadrant elements (expected ~100-300).
__global__ __launch_bounds__(256) void fixup_kernel(
    const float* __restrict__ ref,
    const unsigned* __restrict__ ws,
    const float* __restrict__ q_raw, const float* __restrict__ r_raw,
    const float* __restrict__ qf_raw,
    float* __restrict__ out)
{
    const unsigned n = min(ws[0], (unsigned)CAP);
    const unsigned* list = ws + LIST_OFF;
    for (unsigned j = threadIdx.x; j < n; j += 256) {
        const unsigned idx = list[j];
        const float e0 = ref[5*idx], e1 = ref[5*idx+1], e2 = ref[5*idx+2];
        const float vr = ref[5*idx+3], wr = ref[5*idx+4];
        float K[6];
        riccati_K(vr, wr, q_raw, r_raw, qf_raw, K);
        const float du0 = K[0]*e0 + K[1]*e1 + K[2]*e2;
        const float du1 = K[3]*e0 + K[4]*e1 + K[5]*e2;
        out[2*idx]   = fminf(fmaxf(vr - du0, -V_MAX), V_MAX);
        out[2*idx+1] = fminf(fmaxf(wr - du1, -W_MAX), W_MAX);
    }
}

extern "C" void kernel_launch(void* const* d_in, const int* in_sizes, int n_in,
                              void* d_out, int out_size, void* d_ws, size_t ws_size,
                              hipStream_t stream) {
    const float* ref    = (const float*)d_in[0];
    const float* q_raw  = (const float*)d_in[1];
    const float* r_raw  = (const float*)d_in[2];
    const float* qf_raw = (const float*)d_in[3];
    float* out = (float*)d_out;
    unsigned* ws = (unsigned*)d_ws;

    const int batch = in_sizes[0] / 5;
    const int quads = (batch + 3) / 4;

    table_kernel<<<(NODES + 255) / 256, 256, 0, stream>>>(q_raw, r_raw, qf_raw, ws);

    const int grid = (quads + 511) / 512;
    lqr_main<<<grid, 512, 0, stream>>>(ref, ws, out, batch);

    fixup_kernel<<<1, 256, 0, stream>>>(ref, ws, q_raw, r_raw, qf_raw, out);
}